// Round 7
// baseline (57.194 us; speedup 1.0000x reference)
//
#include <hip/hip_runtime.h>

#define B 8
#define T 128
#define U 64
#define V 512
#define NEG_INF (-1e30f)

// ---------------------------------------------------------------------------
// Kernel A (prep): per-row max + exponentials.
// Rows 0..B*T-1: emission rows  -> Ebuf[row][v] = exp(e - me), meArr[row] = me
// Rows B*T..  : prediction rows -> Pt[b][v][u] = exp(p - mp)  (TRANSPOSED),
//               pb0[b,u] = p[u,0]-mp, plbl[b,u] = p[u,lbl]-mp.
// One wave per row, 4 waves per block.
// ---------------------------------------------------------------------------
__global__ __launch_bounds__(256) void prep_kernel(
    const float* __restrict__ em, const float* __restrict__ pr,
    const int* __restrict__ labels,
    float* __restrict__ Ebuf, float* __restrict__ Pt,
    float* __restrict__ meArr, float* __restrict__ pb0, float* __restrict__ plbl)
{
    const int row  = blockIdx.x * 4 + (threadIdx.x >> 6);
    const int lane = threadIdx.x & 63;

    if (row < B * T) {
        const float* src = em + (size_t)row * V;
        const float4* s4 = (const float4*)(src + lane * 8);
        const float4 xa = s4[0], xb = s4[1];
        float x[8] = {xa.x, xa.y, xa.z, xa.w, xb.x, xb.y, xb.z, xb.w};
        float m = fmaxf(fmaxf(fmaxf(x[0], x[1]), fmaxf(x[2], x[3])),
                        fmaxf(fmaxf(x[4], x[5]), fmaxf(x[6], x[7])));
        #pragma unroll
        for (int d = 1; d < 64; d <<= 1) m = fmaxf(m, __shfl_xor(m, d));
        float4 oa, ob;
        oa.x = __expf(x[0] - m); oa.y = __expf(x[1] - m);
        oa.z = __expf(x[2] - m); oa.w = __expf(x[3] - m);
        ob.x = __expf(x[4] - m); ob.y = __expf(x[5] - m);
        ob.z = __expf(x[6] - m); ob.w = __expf(x[7] - m);
        float4* d4 = (float4*)(Ebuf + (size_t)row * V + lane * 8);
        d4[0] = oa; d4[1] = ob;
        if (lane == 0) meArr[row] = m;
    } else {
        const int prow = row - B * T;          // = b*U + u
        const int b = prow / U, u = prow % U;
        const float* src = pr + (size_t)prow * V;
        const float4* s4 = (const float4*)(src + lane * 8);
        const float4 xa = s4[0], xb = s4[1];
        float x[8] = {xa.x, xa.y, xa.z, xa.w, xb.x, xb.y, xb.z, xb.w};
        float m = fmaxf(fmaxf(fmaxf(x[0], x[1]), fmaxf(x[2], x[3])),
                        fmaxf(fmaxf(x[4], x[5]), fmaxf(x[6], x[7])));
        #pragma unroll
        for (int d = 1; d < 64; d <<= 1) m = fmaxf(m, __shfl_xor(m, d));
        // transposed scatter: Pt[b][v][u], v = lane*8+j (stride-U dword stores)
        float* base = Pt + ((size_t)b * V + lane * 8) * U + u;
        #pragma unroll
        for (int j = 0; j < 8; ++j) base[(size_t)j * U] = __expf(x[j] - m);
        if (lane == 0) {
            pb0[prow] = src[0] - m;
            if (u < U - 1) {
                const int lbl = labels[b * (U - 1) + u];
                plbl[prow] = src[lbl] - m;
            }
        }
    }
}

// ---------------------------------------------------------------------------
// Kernel B (joint): lane = u; per block (b, t-pair) compute
//   S[t,u] = dot(E[t,:], Pt[:,u])  (512 FMAs, coalesced Pt reads,
//   wave-uniform E reads -> scalar loads), then
//   blank_lp = (e0-me) + pb0 - logS ; label_lp = (e[lbl]-me) + plbl - logS.
// ---------------------------------------------------------------------------
__global__ __launch_bounds__(64) void joint_kernel(
    const float* __restrict__ em, const int* __restrict__ labels,
    const float* __restrict__ Ebuf, const float* __restrict__ Pt,
    const float* __restrict__ meArr, const float* __restrict__ pb0,
    const float* __restrict__ plbl,
    float* __restrict__ blank_lp, float* __restrict__ label_lp)
{
    const int lane = threadIdx.x;            // = u
    const int b  = blockIdx.x / (T / 2);
    const int t0 = (blockIdx.x % (T / 2)) * 2;

    const float* E0  = Ebuf + ((size_t)b * T + t0) * V;
    const float* E1  = E0 + V;
    const float* PtP = Pt + (size_t)b * V * U + lane;

    float acc0 = 0.0f, acc1 = 0.0f;
    #pragma unroll 8
    for (int v = 0; v < V; ++v) {
        const float pv = PtP[(size_t)v * U];
        acc0 = fmaf(E0[v], pv, acc0);
        acc1 = fmaf(E1[v], pv, acc1);
    }

    const float pb = pb0[b * U + lane];
    const int   lbl = (lane < U - 1) ? labels[b * (U - 1) + lane] : 0;
    const float pl  = (lane < U - 1) ? plbl[b * U + lane] : 0.0f;

    #pragma unroll
    for (int tt = 0; tt < 2; ++tt) {
        const int t = t0 + tt;
        const float S = tt ? acc1 : acc0;
        const float logS = __logf(S);
        const float me_t = meArr[b * T + t];
        const float* erow = em + ((size_t)b * T + t) * V;
        const float e0 = erow[0];
        const size_t o = ((size_t)b * T + t) * U + lane;
        blank_lp[o] = (e0 - me_t) + pb - logS;
        if (lane < U - 1)
            label_lp[o] = (erow[lbl] - me_t) + pl - logS;
    }
}

// ---------------------------------------------------------------------------
// Kernel C (alpha): anti-diagonal wavefront, 1 recursion wave per batch.
// 256 threads: all 4 waves stage 128 KB to LDS, waves 1-3 retire.
// Per step: shfl_up + fast LSE; next step's LDS values prefetched BEFORE the
// LSE so ds_read latency overlaps the chain (addresses depend only on d).
// ---------------------------------------------------------------------------
__global__ __launch_bounds__(256) void alpha_kernel(
    const float* __restrict__ blank_lp, const float* __restrict__ label_lp,
    const int* __restrict__ in_len, const int* __restrict__ lab_len,
    float* __restrict__ out)
{
    __shared__ float blankL[T * U];   // 32 KB
    __shared__ float labelL[T * U];   // 32 KB

    const int b = blockIdx.x;

    const float4* gb = (const float4*)(blank_lp + (size_t)b * T * U);
    const float4* gl = (const float4*)(label_lp + (size_t)b * T * U);
    float4* sb = (float4*)blankL;
    float4* sl = (float4*)labelL;
    for (int i = threadIdx.x; i < (T * U) / 4; i += 256) {
        sb[i] = gb[i];
        sl[i] = gl[i];
    }
    __syncthreads();
    if (threadIdx.x >= 64) return;

    const int u  = threadIdx.x;
    const int Tb = in_len[b];
    const int Ub = lab_len[b];
    const int lcol = (u == 0) ? 0 : (u - 1);

    // clamped LDS indices for diagonal d (junk reads masked by ternaries)
    auto idxB = [&](int d) { int tm = d - 1 - u; tm = tm < 0 ? 0 : (tm > T - 1 ? T - 1 : tm); return tm * U + u; };
    auto idxL = [&](int d) { int tc = d - u;     tc = tc < 0 ? 0 : (tc > T - 1 ? T - 1 : tc); return tc * U + lcol; };

    float a = (u == 0) ? 0.0f : NEG_INF;
    const int dmax = (Tb - 1) + Ub;

    float blk = blankL[idxB(1)];
    float lbl = labelL[idxL(1)];

    for (int d = 1; d <= dmax; ++d) {
        const float left = __shfl_up(a, 1);     // issues first (ds_bpermute)
        const float blkN = blankL[idxB(d + 1)]; // prefetch next step
        const float lblN = labelL[idxL(d + 1)];

        const int tc = d - u;
        const float up = (tc >= 1) ? (a + blk) : NEG_INF;
        const float lf = (u >= 1 && tc >= 0) ? (left + lbl) : NEG_INF;

        const float mx = fmaxf(up, lf);
        const float dd = fminf(up, lf) - mx;     // <= 0, finite
        const float na = mx + __logf(1.0f + __expf(dd));
        a = (tc >= 0) ? na : a;

        blk = blkN; lbl = lblN;
    }

    if (u == Ub) out[b] = -(a + blankL[(Tb - 1) * U + u]);
}

extern "C" void kernel_launch(void* const* d_in, const int* in_sizes, int n_in,
                              void* d_out, int out_size, void* d_ws, size_t ws_size,
                              hipStream_t stream) {
    const float* em      = (const float*)d_in[0];  // (B,T,V)
    const float* pr      = (const float*)d_in[1];  // (B,U,V)
    const int*   labels  = (const int*)d_in[2];    // (B,U-1)
    const int*   in_len  = (const int*)d_in[3];    // (B,)
    const int*   lab_len = (const int*)d_in[4];    // (B,)
    float* out = (float*)d_out;                    // (B,)

    float* ws = (float*)d_ws;
    float* blank_lp = ws;                    ws += (size_t)B * T * U;  // 65536
    float* label_lp = ws;                    ws += (size_t)B * T * U;  // 65536
    float* Ebuf     = ws;                    ws += (size_t)B * T * V;  // 524288
    float* Pt       = ws;                    ws += (size_t)B * V * U;  // 262144
    float* meArr    = ws;                    ws += (size_t)B * T;      // 1024
    float* pb0      = ws;                    ws += (size_t)B * U;      // 512
    float* plbl     = ws;                    ws += (size_t)B * U;      // 512

    prep_kernel<<<(B * T + B * U) / 4, 256, 0, stream>>>(em, pr, labels, Ebuf, Pt, meArr, pb0, plbl);
    joint_kernel<<<B * T / 2, 64, 0, stream>>>(em, labels, Ebuf, Pt, meArr, pb0, plbl, blank_lp, label_lp);
    alpha_kernel<<<B, 256, 0, stream>>>(blank_lp, label_lp, in_len, lab_len, out);
}

// Round 9
// 43.761 us; speedup vs baseline: 1.3070x; 1.3070x over previous
//
#include <hip/hip_runtime.h>

#define B 8
#define T 128
#define U 64
#define V 512
#define NEG_INF (-1e30f)
#define L2E 1.4426950408889634f
#define LN2 0.6931471805599453f

// ---- DPP wave-64 reductions (pure VALU pipe; gfx9 ctrl encodings) ----------
template<int CTRL, int ROWM>
__device__ __forceinline__ float dpp_movf(float x, int old_bits) {
    int r = __builtin_amdgcn_update_dpp(old_bits, __builtin_bit_cast(int, x),
                                        CTRL, ROWM, 0xF, false);
    return __builtin_bit_cast(float, r);
}
// sum of all 64 lanes -> lane 63 (invalid source lanes contribute old=0)
__device__ __forceinline__ float wave_sum63(float x) {
    x += dpp_movf<0x111, 0xF>(x, 0);   // row_shr:1
    x += dpp_movf<0x112, 0xF>(x, 0);   // row_shr:2
    x += dpp_movf<0x114, 0xF>(x, 0);   // row_shr:4
    x += dpp_movf<0x118, 0xF>(x, 0);   // row_shr:8
    x += dpp_movf<0x142, 0xA>(x, 0);   // row_bcast:15 -> rows 1,3
    x += dpp_movf<0x143, 0xC>(x, 0);   // row_bcast:31 -> rows 2,3
    return x;
}
// max of all 64 lanes -> lane 63 (invalid lanes contribute -inf)
__device__ __forceinline__ float wave_max63(float x) {
    const int NI = (int)0xff800000u;   // -inf bits
    x = fmaxf(x, dpp_movf<0x111, 0xF>(x, NI));
    x = fmaxf(x, dpp_movf<0x112, 0xF>(x, NI));
    x = fmaxf(x, dpp_movf<0x114, 0xF>(x, NI));
    x = fmaxf(x, dpp_movf<0x118, 0xF>(x, NI));
    x = fmaxf(x, dpp_movf<0x142, 0xA>(x, NI));
    x = fmaxf(x, dpp_movf<0x143, 0xC>(x, NI));
    return x;
}
__device__ __forceinline__ float rdlane(float x, int lane) {
    return __builtin_bit_cast(float,
        __builtin_amdgcn_readlane(__builtin_bit_cast(int, x), lane));
}

// ---------------------------------------------------------------------------
// K1 (fused): per block = (b, 4 consecutive t).  Build Pexp[u][v]=exp(p-mp)
// in LDS once (128 KB), then each wave computes its t-row's S[t,u] =
// dot(Ee, Pexp[u]) for all u via DPP-sum; writes log2-domain blank/label lp.
//   blank2[t,u] = (e0-me)L2E + (p0-mp)L2E - log2(S)
//   label2[t,u] = (e[lbl]-me)L2E + (p[lbl]-mp)L2E - log2(S)
// (log_softmax identity: Z = me+mp+ln S)
// ---------------------------------------------------------------------------
__global__ __launch_bounds__(256) void lp_kernel(
    const float* __restrict__ em, const float* __restrict__ pr,
    const int* __restrict__ labels,
    float* __restrict__ blank2, float* __restrict__ label2)
{
    __shared__ float PexpL[U * V];     // 128 KB
    __shared__ float pb0L[U];
    __shared__ float plblL[U];

    const int b    = blockIdx.x >> 5;                        // /32
    const int t    = ((blockIdx.x & 31) << 2) | (threadIdx.x >> 6);
    const int lane = threadIdx.x & 63;
    const int wave = threadIdx.x >> 6;

    // ---- build Pexp: wave handles rows u = wave*16 .. wave*16+15
    for (int r = 0; r < 16; ++r) {
        const int u = wave * 16 + r;
        const float* prow = pr + ((size_t)b * U + u) * V;
        const float4 xa = ((const float4*)(prow + lane * 8))[0];
        const float4 xb = ((const float4*)(prow + lane * 8))[1];
        float x[8] = {xa.x, xa.y, xa.z, xa.w, xb.x, xb.y, xb.z, xb.w};
        float ml = fmaxf(fmaxf(fmaxf(x[0], x[1]), fmaxf(x[2], x[3])),
                         fmaxf(fmaxf(x[4], x[5]), fmaxf(x[6], x[7])));
        const float mp = rdlane(wave_max63(ml), 63);
        float4 oa, ob;
        oa.x = __expf(x[0] - mp); oa.y = __expf(x[1] - mp);
        oa.z = __expf(x[2] - mp); oa.w = __expf(x[3] - mp);
        ob.x = __expf(x[4] - mp); ob.y = __expf(x[5] - mp);
        ob.z = __expf(x[6] - mp); ob.w = __expf(x[7] - mp);
        float4* dst = (float4*)&PexpL[(size_t)u * V + lane * 8];
        dst[0] = oa; dst[1] = ob;
        if (lane == 0) {
            pb0L[u] = (prow[0] - mp) * L2E;
            if (u < U - 1) {
                const int lb = labels[b * (U - 1) + u];
                plblL[u] = (prow[lb] - mp) * L2E;
            } else {
                plblL[u] = 0.0f;
            }
        }
    }
    __syncthreads();

    // ---- E row for this wave's t (register-resident)
    const float* erow = em + ((size_t)b * T + t) * V;
    const float4 ya = ((const float4*)(erow + lane * 8))[0];
    const float4 yb = ((const float4*)(erow + lane * 8))[1];
    float e[8] = {ya.x, ya.y, ya.z, ya.w, yb.x, yb.y, yb.z, yb.w};
    float ml = fmaxf(fmaxf(fmaxf(e[0], e[1]), fmaxf(e[2], e[3])),
                     fmaxf(fmaxf(e[4], e[5]), fmaxf(e[6], e[7])));
    const float me = rdlane(wave_max63(ml), 63);
    const float e0 = rdlane(e[0], 0);          // erow[0] lives in lane 0
    float Ee[8];
    #pragma unroll
    for (int j = 0; j < 8; ++j) Ee[j] = __expf(e[j] - me);

    // ---- dot loop over u: S = sum_v Ee[v] * Pexp[u][v]
    float myS = 1.0f;
    #pragma unroll 4
    for (int u = 0; u < U; ++u) {
        const float4* prow4 = (const float4*)&PexpL[(size_t)u * V + lane * 8];
        const float4 pa = prow4[0];
        const float4 pb = prow4[1];
        float part;
        part = Ee[0] * pa.x;
        part = fmaf(Ee[1], pa.y, part);
        part = fmaf(Ee[2], pa.z, part);
        part = fmaf(Ee[3], pa.w, part);
        part = fmaf(Ee[4], pb.x, part);
        part = fmaf(Ee[5], pb.y, part);
        part = fmaf(Ee[6], pb.z, part);
        part = fmaf(Ee[7], pb.w, part);
        const float S = rdlane(wave_sum63(part), 63);
        if (lane == u) myS = S;
    }

    const float logS2 = __log2f(myS);
    const float e0me2 = (e0 - me) * L2E;
    const size_t o = ((size_t)b * T + t) * U + lane;
    blank2[o] = e0me2 + pb0L[lane] - logS2;
    if (lane < U - 1) {
        const int lb = labels[b * (U - 1) + lane];
        label2[o] = (erow[lb] - me) * L2E + plblL[lane] - logS2;
    }
}

// ---------------------------------------------------------------------------
// K2 (alpha): anti-diagonal wavefront, log2 domain, select-free via -inf
// padding.  blankLP has pad rows at t=-1 and t=T (= NEG_INF); labelS is
// column-shifted (labelS[t][u] = label2[t][u-1], col 0 = NEG_INF) so lane 0
// and pre-lattice lanes self-mask.  Junk values stay finite (~ -k*1e30) and
// exp2(-huge)=0 makes post-mask LSE exact.  Chain/step: shfl_up + add + LSE.
// ---------------------------------------------------------------------------
__global__ __launch_bounds__(256) void alpha_kernel(
    const float* __restrict__ blank2, const float* __restrict__ label2,
    const int* __restrict__ in_len, const int* __restrict__ lab_len,
    float* __restrict__ out)
{
    __shared__ float blankLP[(T + 2) * U];   // rows: [0]=t=-1 pad, [1..T]=t, [T+1]=pad
    __shared__ float labelS[T * U];          // column-shifted

    const int b   = blockIdx.x;
    const int tid = threadIdx.x;

    const float* gb = blank2 + (size_t)b * T * U;
    const float* gl = label2 + (size_t)b * T * U;
    // interior blank rows (float4, both aligned: offset U floats = 256 B)
    float4* sb = (float4*)(blankLP + U);
    const float4* gb4 = (const float4*)gb;
    for (int i = tid; i < (T * U) / 4; i += 256) sb[i] = gb4[i];
    // pad rows
    if (tid < 2 * U) {
        const int r = (tid < U) ? 0 : (T + 1);
        blankLP[r * U + (tid & (U - 1))] = NEG_INF;
    }
    // label, shifted one column right; col 0 = -inf
    for (int i = tid; i < T * U; i += 256) {
        labelS[i] = (i & (U - 1)) ? gl[i - 1] : NEG_INF;
    }
    __syncthreads();
    if (tid >= 64) return;

    const int u  = tid;
    const int Tb = in_len[b];
    const int Ub = lab_len[b];
    const int dmax = (Tb - 1) + Ub;

    // clamped padded indices; address math depends only on (d,u) -> off-chain
    auto idxB = [&](int d) {
        int tm = d - 1 - u;
        tm = tm < -1 ? -1 : (tm > T ? T : tm);
        return (tm + 1) * U + u;
    };
    auto idxL = [&](int d) {
        int tc = d - u;
        tc = tc < 0 ? 0 : (tc > T - 1 ? T - 1 : tc);
        return tc * U + u;
    };

    float a = (u == 0) ? 0.0f : NEG_INF;
    float blk = blankLP[idxB(1)];
    float lbl = labelS[idxL(1)];

    for (int d = 1; d <= dmax; ++d) {
        const float left = __shfl_up(a, 1);        // lane0: own a, masked by lbl=-inf
        const float blkN = blankLP[idxB(d + 1)];   // prefetch next step
        const float lblN = labelS[idxL(d + 1)];

        const float up = a + blk;
        const float lf = left + lbl;
        const float mx = fmaxf(up, lf);
        const float mn = fminf(up, lf);
        a = mx + __log2f(1.0f + exp2f(mn - mx));   // exact when mn-mx = -huge

        blk = blkN; lbl = lblN;
    }

    if (u == Ub) out[b] = -(a + blankLP[Tb * U + u]) * LN2;
}

extern "C" void kernel_launch(void* const* d_in, const int* in_sizes, int n_in,
                              void* d_out, int out_size, void* d_ws, size_t ws_size,
                              hipStream_t stream) {
    const float* em      = (const float*)d_in[0];  // (B,T,V)
    const float* pr      = (const float*)d_in[1];  // (B,U,V)
    const int*   labels  = (const int*)d_in[2];    // (B,U-1)
    const int*   in_len  = (const int*)d_in[3];    // (B,)
    const int*   lab_len = (const int*)d_in[4];    // (B,)
    float* out = (float*)d_out;                    // (B,)

    float* blank2 = (float*)d_ws;                    // B*T*U floats (log2 domain)
    float* label2 = blank2 + (size_t)B * T * U;      // B*T*U floats

    lp_kernel<<<B * T / 4, 256, 0, stream>>>(em, pr, labels, blank2, label2);
    alpha_kernel<<<B, 256, 0, stream>>>(blank2, label2, in_len, lab_len, out);
}

// Round 10
// 31.502 us; speedup vs baseline: 1.8156x; 1.3892x over previous
//
#include <hip/hip_runtime.h>

#define B 8
#define T 128
#define U 64
#define V 512
#define LN2 0.6931471805599453f

// ---- DPP wave-64 helpers (VALU pipe; gfx9/CDNA ctrl encodings) -------------
template<int CTRL, int ROWM>
__device__ __forceinline__ float dpp_movf(float x, int old_bits) {
    int r = __builtin_amdgcn_update_dpp(old_bits, __builtin_bit_cast(int, x),
                                        CTRL, ROWM, 0xF, false);
    return __builtin_bit_cast(float, r);
}
// sum of all 64 lanes -> valid in lane 63
__device__ __forceinline__ float wave_sum63(float x) {
    x += dpp_movf<0x111, 0xF>(x, 0);   // row_shr:1
    x += dpp_movf<0x112, 0xF>(x, 0);   // row_shr:2
    x += dpp_movf<0x114, 0xF>(x, 0);   // row_shr:4
    x += dpp_movf<0x118, 0xF>(x, 0);   // row_shr:8
    x += dpp_movf<0x142, 0xA>(x, 0);   // row_bcast:15 -> rows 1,3
    x += dpp_movf<0x143, 0xC>(x, 0);   // row_bcast:31 -> rows 2,3
    return x;
}
// max of all 64 lanes -> valid in lane 63
__device__ __forceinline__ float wave_max63(float x) {
    const int NI = (int)0xff800000u;   // -inf
    x = fmaxf(x, dpp_movf<0x111, 0xF>(x, NI));
    x = fmaxf(x, dpp_movf<0x112, 0xF>(x, NI));
    x = fmaxf(x, dpp_movf<0x114, 0xF>(x, NI));
    x = fmaxf(x, dpp_movf<0x118, 0xF>(x, NI));
    x = fmaxf(x, dpp_movf<0x142, 0xA>(x, NI));
    x = fmaxf(x, dpp_movf<0x143, 0xC>(x, NI));
    return x;
}
__device__ __forceinline__ float rdlane(float x, int lane) {
    return __builtin_bit_cast(float,
        __builtin_amdgcn_readlane(__builtin_bit_cast(int, x), lane));
}
// wave shift right by 1: lane u <- lane u-1; lane 0 <- 0.0f (old=0)
__device__ __forceinline__ float dpp_shr1(float x) {
    int r = __builtin_amdgcn_update_dpp(0, __builtin_bit_cast(int, x),
                                        0x138, 0xF, 0xF, false); // wave_shr:1
    return __builtin_bit_cast(float, r);
}

// ---------------------------------------------------------------------------
// K1: joint softmax, factorized + probability-domain output.
//   S[t,u] = dot(exp(e[t]-me), exp(p[u]-mp));  blankP = exp(e0-me)*Pexp[u][0]/S
//   labelP = exp(e[lbl]-me)*Pexp[u][lbl]/S
// Grid: 256 blocks = (b:8) x (tg:16) x (ug:2); 256 thr.  Pexp[32][512] = 64 KB.
// Each wave: builds 8 P-rows, then owns 2 t's x 32 u's; Pexp rows read as
// contiguous 1KB ds_read_b128 sweeps (conflict-free); DPP-tree reductions.
// ---------------------------------------------------------------------------
__global__ __launch_bounds__(256) void lp_kernel(
    const float* __restrict__ em, const float* __restrict__ pr,
    const int* __restrict__ labels,
    float* __restrict__ blankP, float* __restrict__ labelP)
{
    __shared__ float Pexp[32][V];      // 64 KB

    const int bid  = blockIdx.x;
    const int ug   = bid & 1;
    const int tg   = (bid >> 1) & 15;
    const int b    = bid >> 5;
    const int lane = threadIdx.x & 63;
    const int wave = threadIdx.x >> 6;

    // ---- build: 8 prediction rows per wave
    #pragma unroll 2
    for (int r = 0; r < 8; ++r) {
        const int ul = wave * 8 + r;
        const int gu = ug * 32 + ul;
        const float* prow = pr + ((size_t)b * U + gu) * V;
        const float4 xa = ((const float4*)prow)[lane];       // v = 4*lane..+3
        const float4 xb = ((const float4*)prow)[64 + lane];  // v = 256+4*lane..
        float m = fmaxf(fmaxf(fmaxf(xa.x, xa.y), fmaxf(xa.z, xa.w)),
                        fmaxf(fmaxf(xb.x, xb.y), fmaxf(xb.z, xb.w)));
        const float mp = rdlane(wave_max63(m), 63);
        float4 oa, ob;
        oa.x = __expf(xa.x - mp); oa.y = __expf(xa.y - mp);
        oa.z = __expf(xa.z - mp); oa.w = __expf(xa.w - mp);
        ob.x = __expf(xb.x - mp); ob.y = __expf(xb.y - mp);
        ob.z = __expf(xb.z - mp); ob.w = __expf(xb.w - mp);
        ((float4*)&Pexp[ul][0])[lane]      = oa;
        ((float4*)&Pexp[ul][0])[64 + lane] = ob;
    }
    __syncthreads();

    // ---- emission rows t0, t1 (register-resident)
    const int t0 = tg * 8 + wave * 2;
    const int t1 = t0 + 1;
    const float* er0 = em + ((size_t)b * T + t0) * V;
    const float* er1 = em + ((size_t)b * T + t1) * V;
    const float4 ea0 = ((const float4*)er0)[lane];
    const float4 eb0 = ((const float4*)er0)[64 + lane];
    const float4 ea1 = ((const float4*)er1)[lane];
    const float4 eb1 = ((const float4*)er1)[64 + lane];
    float m0 = fmaxf(fmaxf(fmaxf(ea0.x, ea0.y), fmaxf(ea0.z, ea0.w)),
                     fmaxf(fmaxf(eb0.x, eb0.y), fmaxf(eb0.z, eb0.w)));
    float m1 = fmaxf(fmaxf(fmaxf(ea1.x, ea1.y), fmaxf(ea1.z, ea1.w)),
                     fmaxf(fmaxf(eb1.x, eb1.y), fmaxf(eb1.z, eb1.w)));
    const float me0 = rdlane(wave_max63(m0), 63);
    const float me1 = rdlane(wave_max63(m1), 63);
    float E0[8], E1[8];
    E0[0] = __expf(ea0.x - me0); E0[1] = __expf(ea0.y - me0);
    E0[2] = __expf(ea0.z - me0); E0[3] = __expf(ea0.w - me0);
    E0[4] = __expf(eb0.x - me0); E0[5] = __expf(eb0.y - me0);
    E0[6] = __expf(eb0.z - me0); E0[7] = __expf(eb0.w - me0);
    E1[0] = __expf(ea1.x - me1); E1[1] = __expf(ea1.y - me1);
    E1[2] = __expf(ea1.z - me1); E1[3] = __expf(ea1.w - me1);
    E1[4] = __expf(eb1.x - me1); E1[5] = __expf(eb1.y - me1);
    E1[6] = __expf(eb1.z - me1); E1[7] = __expf(eb1.w - me1);

    // ---- dot loop: one Pexp-row read feeds both t's
    float S0 = 1.0f, S1 = 1.0f;
    #pragma unroll 2
    for (int ul = 0; ul < 32; ++ul) {
        const float4 pa = ((const float4*)&Pexp[ul][0])[lane];
        const float4 pb = ((const float4*)&Pexp[ul][0])[64 + lane];
        float p0 = E0[0] * pa.x;
        p0 = fmaf(E0[1], pa.y, p0); p0 = fmaf(E0[2], pa.z, p0);
        p0 = fmaf(E0[3], pa.w, p0); p0 = fmaf(E0[4], pb.x, p0);
        p0 = fmaf(E0[5], pb.y, p0); p0 = fmaf(E0[6], pb.z, p0);
        p0 = fmaf(E0[7], pb.w, p0);
        float p1 = E1[0] * pa.x;
        p1 = fmaf(E1[1], pa.y, p1); p1 = fmaf(E1[2], pa.z, p1);
        p1 = fmaf(E1[3], pa.w, p1); p1 = fmaf(E1[4], pb.x, p1);
        p1 = fmaf(E1[5], pb.y, p1); p1 = fmaf(E1[6], pb.z, p1);
        p1 = fmaf(E1[7], pb.w, p1);
        const float s0 = rdlane(wave_sum63(p0), 63);
        const float s1 = rdlane(wave_sum63(p1), 63);
        if (lane == ul) { S0 = s0; S1 = s1; }
    }

    // ---- epilogue: lanes 0..31 own u = ug*32+lane
    if (lane < 32) {
        const int gu = ug * 32 + lane;
        const float Ppb = Pexp[lane][0];
        const float r0 = 1.0f / S0, r1 = 1.0f / S1;
        const float ebl0 = __expf(er0[0] - me0);
        const float ebl1 = __expf(er1[0] - me1);
        const size_t o0 = ((size_t)b * T + t0) * U + gu;
        const size_t o1 = o0 + U;
        blankP[o0] = ebl0 * Ppb * r0;
        blankP[o1] = ebl1 * Ppb * r1;
        if (gu < U - 1) {
            const int lb = labels[b * (U - 1) + gu];
            const float Ppl = Pexp[lane][lb];
            labelP[o0] = __expf(er0[lb] - me0) * Ppl * r0;
            labelP[o1] = __expf(er1[lb] - me1) * Ppl * r1;
        }
    }
}

// ---------------------------------------------------------------------------
// K2: anti-diagonal alpha recursion in PROBABILITY domain.
//   A[u] <- A[u]*bk(t-1,u) + A[u-1]*lb(t,u-1)     (junk/pad cells are 0)
// left-neighbor via DPP wave_shr:1 (VALU, ~8cy — replaces 120cy ds_bpermute).
// Power-of-2 rescale every 4 steps (exact; max re-centered at 2^30).
// LDS operands software-pipelined 8 diagonals ahead (static ring, unrolled).
// ---------------------------------------------------------------------------
__global__ __launch_bounds__(256) void alpha_kernel(
    const float* __restrict__ blankP, const float* __restrict__ labelP,
    const int* __restrict__ in_len, const int* __restrict__ lab_len,
    float* __restrict__ out)
{
    __shared__ float blankQ[(T + 2) * U];  // row r = t+1; rows 0, T+1 = 0
    __shared__ float labelQ[T * U];        // labelQ[t][u] = labelP[t][u-1]; col0=0

    const int b   = blockIdx.x;
    const int tid = threadIdx.x;

    const float* gb = blankP + (size_t)b * T * U;
    const float* gl = labelP + (size_t)b * T * U;
    float4* sb = (float4*)(blankQ + U);
    const float4* gb4 = (const float4*)gb;
    for (int i = tid; i < (T * U) / 4; i += 256) sb[i] = gb4[i];
    if (tid < 2 * U) {
        const int r = (tid < U) ? 0 : (T + 1);
        blankQ[r * U + (tid & (U - 1))] = 0.0f;
    }
    for (int i = tid; i < T * U; i += 256)
        labelQ[i] = (i & (U - 1)) ? gl[i - 1] : 0.0f;
    __syncthreads();
    if (tid >= 64) return;

    const int u  = tid;
    const int Tb = in_len[b];
    const int Ub = lab_len[b];
    const int dmax = (Tb - 1) + Ub;

    auto ib = [&](int d) {                       // blank at (t-1, u), padded+clamped
        int tm = d - 1 - u;
        tm = min(max(tm, -1), T);
        return (tm + 1) * U + u;
    };
    auto il = [&](int d) {                       // label at (t, u-1), shifted+clamped
        int tc = d - u;
        tc = min(max(tc, 0), T - 1);
        return tc * U + u;
    };

    float A = (u == 0) ? 1.0f : 0.0f;            // alpha[0,0] = 1
    int   off = 0;                                // true alpha = A * 2^off
    float aCap = 1.0f;
    int   offCap = 0;

    float cb[8], cl[8], nb[8], nl[8];
    #pragma unroll
    for (int j = 0; j < 8; ++j) { cb[j] = blankQ[ib(1 + j)]; cl[j] = labelQ[il(1 + j)]; }

    for (int d0 = 1; d0 <= 185; d0 += 8) {       // d = 1..192 (dmax <= 190)
        #pragma unroll
        for (int j = 0; j < 8; ++j) {
            nb[j] = blankQ[ib(d0 + 8 + j)];      // prefetch next group
            nl[j] = labelQ[il(d0 + 8 + j)];
            const float left = dpp_shr1(A);
            A = fmaf(A, cb[j], left * cl[j]);
            if ((j & 3) == 3) {                  // rescale every 4 steps
                const float mx = rdlane(wave_max63(A), 63);
                int e = ((__builtin_bit_cast(int, mx) >> 23) & 255) - 127;
                e = max(e, -96);                 // keep 2^(30-e) representable
                A *= __builtin_bit_cast(float, (157 - e) << 23);  // max -> ~2^30
                off += e - 30;
            }
            const bool cap = (d0 + j == dmax);
            aCap   = cap ? A   : aCap;
            offCap = cap ? off : offCap;
        }
        #pragma unroll
        for (int j = 0; j < 8; ++j) { cb[j] = nb[j]; cl[j] = nl[j]; }
    }

    if (u == Ub) {
        const float bprob = blankQ[Tb * U + u];  // blank at (Tb-1, Ub)
        const float v = __log2f(aCap) + (float)offCap + __log2f(bprob);
        out[b] = -v * LN2;
    }
}

extern "C" void kernel_launch(void* const* d_in, const int* in_sizes, int n_in,
                              void* d_out, int out_size, void* d_ws, size_t ws_size,
                              hipStream_t stream) {
    const float* em      = (const float*)d_in[0];  // (B,T,V)
    const float* pr      = (const float*)d_in[1];  // (B,U,V)
    const int*   labels  = (const int*)d_in[2];    // (B,U-1)
    const int*   in_len  = (const int*)d_in[3];    // (B,)
    const int*   lab_len = (const int*)d_in[4];    // (B,)
    float* out = (float*)d_out;                    // (B,)

    float* blankP = (float*)d_ws;                    // B*T*U floats (probabilities)
    float* labelP = blankP + (size_t)B * T * U;      // B*T*U floats

    lp_kernel<<<B * T / 4, 256, 0, stream>>>(em, pr, labels, blankP, labelP);
    alpha_kernel<<<B, 256, 0, stream>>>(blankP, labelP, in_len, lab_len, out);
}